// Round 4
// baseline (78.246 us; speedup 1.0000x reference)
//
#include <hip/hip_runtime.h>

// QConv2D quanvolution, Heisenberg picture, 4-patches-per-thread eval.
// z_w(patch) = sum_{P in {I,Y,Z}^4} c_{w,P} * prod_q t_q(P_q),
//   t(I)=1, t(Y)=-sin a_q, t(Z)=cos a_q,  c fixed by params.
// setup (1 block) -> W2[p][w] table (81 float4) in d_ws.
// eval: each thread owns 4 consecutive j-columns of one output row, so each
// LDS coefficient read (ds_read_b128 broadcast) is amortized over 4 patches:
// DS instr/patch drops 4x vs R3 (the suspected eval bottleneck; R3 showed
// LDS-vs-global W made no difference, VALU alone is ~3.5us device-wide).
// Wire q <-> state bit (8>>q).

#define HH 128
#define WW 128
#define HO 127
#define WO 127
#define BB 32
#define JSLOTS 32   // ceil(127/4) thread-slots per row

template <int M>
__device__ __forceinline__ void rx_gate(float* re, float* im, float th) {
    float s, c;
    __sincosf(th * 0.5f, &s, &c);
#pragma unroll
    for (int idx = 0; idx < 16; ++idx) {
        if (idx & M) continue;
        const int p = idx | M;
        float r0 = re[idx], i0 = im[idx], r1 = re[p], i1 = im[p];
        re[idx] = fmaf(c, r0, s * i1);
        im[idx] = fmaf(c, i0, -s * r1);
        re[p]   = fmaf(c, r1, s * i0);
        im[p]   = fmaf(c, i1, -s * r0);
    }
}

template <int M>
__device__ __forceinline__ void rz_gate(float* re, float* im, float th) {
    float sp, cp;
    __sincosf(th * 0.5f, &sp, &cp);
#pragma unroll
    for (int idx = 0; idx < 16; ++idx) {
        float r = re[idx], q = im[idx];
        if (idx & M) {
            re[idx] = fmaf(r, cp, -q * sp);
            im[idx] = fmaf(q, cp, r * sp);
        } else {
            re[idx] = fmaf(r, cp, q * sp);
            im[idx] = fmaf(q, cp, -r * sp);
        }
    }
}

template <int CM, int TM>
__device__ __forceinline__ void cnot_gate(float* re, float* im) {
#pragma unroll
    for (int idx = 0; idx < 16; ++idx) {
        if ((idx & CM) && !(idx & TM)) {
            const int p = idx | TM;
            float t;
            t = re[idx]; re[idx] = re[p]; re[p] = t;
            t = im[idx]; im[idx] = im[p]; im[p] = t;
        }
    }
}

__device__ __forceinline__ void param_circuit(float* re, float* im,
                                              const float* __restrict__ prm) {
#pragma unroll
    for (int l = 0; l < 2; ++l) {
        const float* p = prm + l * 8;
        rx_gate<8>(re, im, p[0]); rz_gate<8>(re, im, p[1]);
        rx_gate<4>(re, im, p[2]); rz_gate<4>(re, im, p[3]);
        rx_gate<2>(re, im, p[4]); rz_gate<2>(re, im, p[5]);
        rx_gate<1>(re, im, p[6]); rz_gate<1>(re, im, p[7]);
        cnot_gate<4, 8>(re, im);
        cnot_gate<2, 4>(re, im);
        cnot_gate<1, 2>(re, im);
    }
}

// One block. Phase A: 16 threads simulate U|j> -> LDS. Phase B: 324 threads
// compute W[p*4 + w] = Tr((tensor P) U^dag Z_w U)/16, p base-3 (wire-3 digit
// least significant), digit 0=I,1=Y,2=Z.
__global__ __launch_bounds__(384) void qconv_setup(const float* __restrict__ prm,
                                                   float* __restrict__ W) {
    __shared__ float Ur[16][16];
    __shared__ float Ui[16][16];
    const int tid = threadIdx.x;
    if (tid < 16) {
        float re[16], im[16];
#pragma unroll
        for (int k = 0; k < 16; ++k) { re[k] = (k == tid) ? 1.f : 0.f; im[k] = 0.f; }
        param_circuit(re, im, prm);
#pragma unroll
        for (int k = 0; k < 16; ++k) { Ur[k][tid] = re[k]; Ui[k][tid] = im[k]; }
    }
    __syncthreads();
    if (tid < 324) {
        const int w = tid / 81;
        int p = tid % 81;
        const int pidx = p;
        const int t3 = p % 3; p /= 3;
        const int t2 = p % 3; p /= 3;
        const int t1 = p % 3;
        const int t0 = p / 3;
        const int f = (t0 == 1 ? 8 : 0) | (t1 == 1 ? 4 : 0) |
                      (t2 == 1 ? 2 : 0) | (t3 == 1 ? 1 : 0);
        const int zbit = 8 >> w;
        float acc = 0.f;
        for (int i = 0; i < 16; ++i) {
            float pr = 1.f, pi = 0.f;
            {
                int ib;
                ib = (i >> 3) & 1;
                if (t0 == 2) { if (ib) { pr = -pr; pi = -pi; } }
                else if (t0 == 1) { float tt = pr; if (ib) { pr = -pi; pi = tt; } else { pr = pi; pi = -tt; } }
                ib = (i >> 2) & 1;
                if (t1 == 2) { if (ib) { pr = -pr; pi = -pi; } }
                else if (t1 == 1) { float tt = pr; if (ib) { pr = -pi; pi = tt; } else { pr = pi; pi = -tt; } }
                ib = (i >> 1) & 1;
                if (t2 == 2) { if (ib) { pr = -pr; pi = -pi; } }
                else if (t2 == 1) { float tt = pr; if (ib) { pr = -pi; pi = tt; } else { pr = pi; pi = -tt; } }
                ib = i & 1;
                if (t3 == 2) { if (ib) { pr = -pr; pi = -pi; } }
                else if (t3 == 1) { float tt = pr; if (ib) { pr = -pi; pi = tt; } else { pr = pi; pi = -tt; } }
            }
            const int j = i ^ f;
            float sr = 0.f, si = 0.f;
            for (int k = 0; k < 16; ++k) {
                float zk = (k & zbit) ? -1.f : 1.f;
                float ar = Ur[k][j], ai = Ui[k][j];
                float br = Ur[k][i], bi = Ui[k][i];
                sr += zk * fmaf(ar, br, ai * bi);
                si += zk * fmaf(ar, bi, -ai * br);
            }
            acc += pr * sr - pi * si;
        }
        W[pidx * 4 + w] = acc * (1.0f / 16.0f);  // layout [p][w]
    }
}

__global__ __launch_bounds__(256) void qconv_eval(
    const float* __restrict__ x, const float* __restrict__ W,
    float* __restrict__ out, int total_threads) {
    __shared__ float4 sW[81];
    {
        const float4* Wv = (const float4*)W;
        for (int k = threadIdx.x; k < 81; k += 256) sW[k] = Wv[k];
    }
    __syncthreads();

    int tid = blockIdx.x * blockDim.x + threadIdx.x;
    if (tid >= total_threads) return;

    const int slot = tid % JSLOTS;          // 4-column group within a row
    int t = tid / JSLOTS;
    const int i = t % HO;
    const int b = t / HO;
    const int j0 = slot * 4;                // j0 in {0,4,...,124}; 16B aligned

    const float* row0 = x + ((size_t)b * HH + i) * WW + j0;
    const float* row1 = row0 + WW;
    // need x[i][j0..j0+4], x[i+1][j0..j0+4]; the +4 element is out of range
    // only for slot 31 (j0=124), where patch j=127 doesn't exist anyway.
    const float4 v0 = *(const float4*)row0;
    const float4 v1 = *(const float4*)row1;
    const bool has5 = (j0 + 4 < WW);
    const float x04 = has5 ? row0[4] : 0.f;
    const float x14 = has5 ? row1[4] : 0.f;
    const float r0[5] = {v0.x, v0.y, v0.z, v0.w, x04};
    const float r1[5] = {v1.x, v1.y, v1.z, v1.w, x14};

    // per-patch per-wire basis values: t(I)=1, t(Y)=-sin a, t(Z)=cos a
    float t0v[4][3], t1v[4][3], t2v[4][3], t3v[4][3];
#pragma unroll
    for (int pp = 0; pp < 4; ++pp) {
        float s, c;
        __sincosf(r0[pp], &s, &c);     t0v[pp][0] = 1.f; t0v[pp][1] = -s; t0v[pp][2] = c;
        __sincosf(r0[pp + 1], &s, &c); t1v[pp][0] = 1.f; t1v[pp][1] = -s; t1v[pp][2] = c;
        __sincosf(r1[pp], &s, &c);     t2v[pp][0] = 1.f; t2v[pp][1] = -s; t2v[pp][2] = c;
        __sincosf(r1[pp + 1], &s, &c); t3v[pp][0] = 1.f; t3v[pp][1] = -s; t3v[pp][2] = c;
    }

    float acc[4][4];  // [patch][wire]
#pragma unroll
    for (int pp = 0; pp < 4; ++pp)
#pragma unroll
        for (int w = 0; w < 4; ++w) acc[pp][w] = 0.f;

#pragma unroll
    for (int p0 = 0; p0 < 3; ++p0) {
        float g0[4];
#pragma unroll
        for (int pp = 0; pp < 4; ++pp) g0[pp] = t0v[pp][p0];
#pragma unroll
        for (int p1 = 0; p1 < 3; ++p1) {
            float g1[4];
#pragma unroll
            for (int pp = 0; pp < 4; ++pp) g1[pp] = g0[pp] * t1v[pp][p1];
#pragma unroll
            for (int p2 = 0; p2 < 3; ++p2) {
                float g2[4];
#pragma unroll
                for (int pp = 0; pp < 4; ++pp) g2[pp] = g1[pp] * t2v[pp][p2];
#pragma unroll
                for (int p3 = 0; p3 < 3; ++p3) {
                    const int p = ((p0 * 3 + p1) * 3 + p2) * 3 + p3;
                    const float4 q = sW[p];  // one DS read feeds 4 patches
#pragma unroll
                    for (int pp = 0; pp < 4; ++pp) {
                        const float g = g2[pp] * t3v[pp][p3];
                        acc[pp][0] = fmaf(g, q.x, acc[pp][0]);
                        acc[pp][1] = fmaf(g, q.y, acc[pp][1]);
                        acc[pp][2] = fmaf(g, q.z, acc[pp][2]);
                        acc[pp][3] = fmaf(g, q.w, acc[pp][3]);
                    }
                }
            }
        }
    }

    const int npatch = (j0 + 4 <= WO) ? 4 : (WO - j0);  // slot 31 -> 3
    float* obase = out + (((size_t)b * 4) * HO + (size_t)i) * WO + j0;
#pragma unroll
    for (int w = 0; w < 4; ++w) {
        float* o = obase + (size_t)w * HO * WO;
        for (int pp = 0; pp < npatch; ++pp) o[pp] = acc[pp][w];
    }
}

extern "C" void kernel_launch(void* const* d_in, const int* in_sizes, int n_in,
                              void* d_out, int out_size, void* d_ws, size_t ws_size,
                              hipStream_t stream) {
    const float* x = (const float*)d_in[0];
    const float* prm = (const float*)d_in[1];
    float* out = (float*)d_out;
    float* W = (float*)d_ws;  // 324 floats, layout [p][w]

    qconv_setup<<<1, 384, 0, stream>>>(prm, W);

    const int total_threads = BB * HO * JSLOTS;  // 130048
    const int blocks = (total_threads + 255) / 256;
    qconv_eval<<<blocks, 256, 0, stream>>>(x, W, out, total_threads);
}

// Round 5
// 70.701 us; speedup vs baseline: 1.1067x; 1.1067x over previous
//
#include <hip/hip_runtime.h>

// QConv2D quanvolution — single fused kernel.
// Heisenberg picture: z_w(patch) = sum_{P in {I,Y,Z}^4} c_{w,P} * prod_q t_q(P_q),
//   t(I)=1, t(Y)=-sin a_q, t(Z)=cos a_q;  c_{w,P} fixed by params.
// Every block redundantly computes the 81x4 coefficient table (blocks are all
// co-resident, so this adds ~1-2us overlapped, and saves one kernel launch —
// R1 vs R2/3/4 showed the two-launch structure costs ~3us while eval-side
// optimizations moved nothing).
//   Phase A : threads 0-15 simulate U columns -> LDS (wave 0 only, no barriers)
//   Phase B1: 256 threads build M_w = U^dag Z_w U (4x16x16 complex) in LDS
//   Phase B2: 324 coefficient traces from M (16 terms each, cheap)
//   Phase C : eval, 4 patches per thread (R4 structure)
// Wire q <-> state bit (8>>q).

#define HH 128
#define WW 128
#define HO 127
#define WO 127
#define BB 32
#define JSLOTS 32   // ceil(127/4) 4-column thread-slots per output row

template <int M>
__device__ __forceinline__ void rx_gate(float* re, float* im, float th) {
    float s, c;
    __sincosf(th * 0.5f, &s, &c);
#pragma unroll
    for (int idx = 0; idx < 16; ++idx) {
        if (idx & M) continue;
        const int p = idx | M;
        float r0 = re[idx], i0 = im[idx], r1 = re[p], i1 = im[p];
        re[idx] = fmaf(c, r0, s * i1);
        im[idx] = fmaf(c, i0, -s * r1);
        re[p]   = fmaf(c, r1, s * i0);
        im[p]   = fmaf(c, i1, -s * r0);
    }
}

template <int M>
__device__ __forceinline__ void rz_gate(float* re, float* im, float th) {
    float sp, cp;
    __sincosf(th * 0.5f, &sp, &cp);
#pragma unroll
    for (int idx = 0; idx < 16; ++idx) {
        float r = re[idx], q = im[idx];
        if (idx & M) {
            re[idx] = fmaf(r, cp, -q * sp);
            im[idx] = fmaf(q, cp, r * sp);
        } else {
            re[idx] = fmaf(r, cp, q * sp);
            im[idx] = fmaf(q, cp, -r * sp);
        }
    }
}

template <int CM, int TM>
__device__ __forceinline__ void cnot_gate(float* re, float* im) {
#pragma unroll
    for (int idx = 0; idx < 16; ++idx) {
        if ((idx & CM) && !(idx & TM)) {
            const int p = idx | TM;
            float t;
            t = re[idx]; re[idx] = re[p]; re[p] = t;
            t = im[idx]; im[idx] = im[p]; im[p] = t;
        }
    }
}

__device__ __forceinline__ void param_circuit(float* re, float* im,
                                              const float* __restrict__ prm) {
#pragma unroll
    for (int l = 0; l < 2; ++l) {
        const float* p = prm + l * 8;
        rx_gate<8>(re, im, p[0]); rz_gate<8>(re, im, p[1]);
        rx_gate<4>(re, im, p[2]); rz_gate<4>(re, im, p[3]);
        rx_gate<2>(re, im, p[4]); rz_gate<2>(re, im, p[5]);
        rx_gate<1>(re, im, p[6]); rz_gate<1>(re, im, p[7]);
        cnot_gate<4, 8>(re, im);
        cnot_gate<2, 4>(re, im);
        cnot_gate<1, 2>(re, im);
    }
}

__global__ __launch_bounds__(256) void qconv_fused(
    const float* __restrict__ x, const float* __restrict__ prm,
    float* __restrict__ out) {
    __shared__ float Ur[16][16];   // [row k][col j]
    __shared__ float Ui[16][16];
    __shared__ float Mr[4][16][16];  // M_w[j][i]
    __shared__ float Mi[4][16][16];
    __shared__ float4 sW[81];        // sW[p] = c_{*,P}, one float per wire

    const int tid = threadIdx.x;

    // ---- Phase A: U columns (threads 0-15; wave 0 only, rest wait) ----
    if (tid < 16) {
        float re[16], im[16];
#pragma unroll
        for (int k = 0; k < 16; ++k) { re[k] = (k == tid) ? 1.f : 0.f; im[k] = 0.f; }
        param_circuit(re, im, prm);
#pragma unroll
        for (int k = 0; k < 16; ++k) { Ur[k][tid] = re[k]; Ui[k][tid] = im[k]; }
    }
    __syncthreads();

    // ---- Phase B1: M_w[j][i] = sum_k conj(U[k][j]) z_k U[k][i] ----
    {
        const int w = tid >> 6;            // 0..3
        const int zbit = 8 >> w;
        const int base = (tid & 63) * 4;   // 4 consecutive entries
#pragma unroll
        for (int r = 0; r < 4; ++r) {
            const int e = base + r;
            const int j = e >> 4, i = e & 15;
            float sr = 0.f, si = 0.f;
            for (int k = 0; k < 16; ++k) {
                float zk = (k & zbit) ? -1.f : 1.f;
                float ar = Ur[k][j], ai = Ui[k][j];
                float br = Ur[k][i], bi = Ui[k][i];
                sr += zk * fmaf(ar, br, ai * bi);
                si += zk * fmaf(ar, bi, -ai * br);
            }
            Mr[w][j][i] = sr;
            Mi[w][j][i] = si;
        }
    }
    __syncthreads();

    // ---- Phase B2: coefficient traces (324 of them) ----
    for (int cc = tid; cc < 324; cc += 256) {
        const int w = cc / 81;
        int p = cc % 81;
        const int pidx = p;
        const int t3 = p % 3; p /= 3;
        const int t2 = p % 3; p /= 3;
        const int t1 = p % 3;
        const int t0 = p / 3;
        const int f = (t0 == 1 ? 8 : 0) | (t1 == 1 ? 4 : 0) |
                      (t2 == 1 ? 2 : 0) | (t3 == 1 ? 1 : 0);
        float acc = 0.f;
        for (int i = 0; i < 16; ++i) {
            // phase = P[i][i^f]; entries in {1,-1,i,-i}. Z: diag(1,-1);
            // Y[0][1]=-i, Y[1][0]=+i.
            float pr = 1.f, pi = 0.f;
            int ib;
            ib = (i >> 3) & 1;
            if (t0 == 2) { if (ib) { pr = -pr; pi = -pi; } }
            else if (t0 == 1) { float tt = pr; if (ib) { pr = -pi; pi = tt; } else { pr = pi; pi = -tt; } }
            ib = (i >> 2) & 1;
            if (t1 == 2) { if (ib) { pr = -pr; pi = -pi; } }
            else if (t1 == 1) { float tt = pr; if (ib) { pr = -pi; pi = tt; } else { pr = pi; pi = -tt; } }
            ib = (i >> 1) & 1;
            if (t2 == 2) { if (ib) { pr = -pr; pi = -pi; } }
            else if (t2 == 1) { float tt = pr; if (ib) { pr = -pi; pi = tt; } else { pr = pi; pi = -tt; } }
            ib = i & 1;
            if (t3 == 2) { if (ib) { pr = -pr; pi = -pi; } }
            else if (t3 == 1) { float tt = pr; if (ib) { pr = -pi; pi = tt; } else { pr = pi; pi = -tt; } }
            const int j = i ^ f;
            acc += pr * Mr[w][j][i] - pi * Mi[w][j][i];
        }
        ((float*)sW)[pidx * 4 + w] = acc * (1.0f / 16.0f);
    }
    __syncthreads();

    // ---- Phase C: eval, 4 consecutive output columns per thread ----
    const int tid_g = blockIdx.x * blockDim.x + tid;  // grid is exactly 508*256
    const int slot = tid_g % JSLOTS;
    int t = tid_g / JSLOTS;
    const int i = t % HO;
    const int b = t / HO;
    const int j0 = slot * 4;   // 16B-aligned

    const float* row0 = x + ((size_t)b * HH + i) * WW + j0;
    const float* row1 = row0 + WW;
    const float4 v0 = *(const float4*)row0;
    const float4 v1 = *(const float4*)row1;
    const bool has5 = (j0 + 4 < WW);
    const float x04 = has5 ? row0[4] : 0.f;
    const float x14 = has5 ? row1[4] : 0.f;
    const float r0[5] = {v0.x, v0.y, v0.z, v0.w, x04};
    const float r1[5] = {v1.x, v1.y, v1.z, v1.w, x14};

    float t0v[4][3], t1v[4][3], t2v[4][3], t3v[4][3];
#pragma unroll
    for (int pp = 0; pp < 4; ++pp) {
        float s, c;
        __sincosf(r0[pp], &s, &c);     t0v[pp][0] = 1.f; t0v[pp][1] = -s; t0v[pp][2] = c;
        __sincosf(r0[pp + 1], &s, &c); t1v[pp][0] = 1.f; t1v[pp][1] = -s; t1v[pp][2] = c;
        __sincosf(r1[pp], &s, &c);     t2v[pp][0] = 1.f; t2v[pp][1] = -s; t2v[pp][2] = c;
        __sincosf(r1[pp + 1], &s, &c); t3v[pp][0] = 1.f; t3v[pp][1] = -s; t3v[pp][2] = c;
    }

    float acc[4][4];  // [patch][wire]
#pragma unroll
    for (int pp = 0; pp < 4; ++pp)
#pragma unroll
        for (int w = 0; w < 4; ++w) acc[pp][w] = 0.f;

#pragma unroll
    for (int p0 = 0; p0 < 3; ++p0) {
        float g0[4];
#pragma unroll
        for (int pp = 0; pp < 4; ++pp) g0[pp] = t0v[pp][p0];
#pragma unroll
        for (int p1 = 0; p1 < 3; ++p1) {
            float g1[4];
#pragma unroll
            for (int pp = 0; pp < 4; ++pp) g1[pp] = g0[pp] * t1v[pp][p1];
#pragma unroll
            for (int p2 = 0; p2 < 3; ++p2) {
                float g2[4];
#pragma unroll
                for (int pp = 0; pp < 4; ++pp) g2[pp] = g1[pp] * t2v[pp][p2];
#pragma unroll
                for (int p3 = 0; p3 < 3; ++p3) {
                    const int p = ((p0 * 3 + p1) * 3 + p2) * 3 + p3;
                    const float4 q = sW[p];  // one DS read feeds 4 patches
#pragma unroll
                    for (int pp = 0; pp < 4; ++pp) {
                        const float g = g2[pp] * t3v[pp][p3];
                        acc[pp][0] = fmaf(g, q.x, acc[pp][0]);
                        acc[pp][1] = fmaf(g, q.y, acc[pp][1]);
                        acc[pp][2] = fmaf(g, q.z, acc[pp][2]);
                        acc[pp][3] = fmaf(g, q.w, acc[pp][3]);
                    }
                }
            }
        }
    }

    const int npatch = (j0 + 4 <= WO) ? 4 : (WO - j0);  // slot 31 -> 3
    float* obase = out + (((size_t)b * 4) * HO + (size_t)i) * WO + j0;
#pragma unroll
    for (int w = 0; w < 4; ++w) {
        float* o = obase + (size_t)w * HO * WO;
        for (int pp = 0; pp < npatch; ++pp) o[pp] = acc[pp][w];
    }
}

extern "C" void kernel_launch(void* const* d_in, const int* in_sizes, int n_in,
                              void* d_out, int out_size, void* d_ws, size_t ws_size,
                              hipStream_t stream) {
    const float* x = (const float*)d_in[0];
    const float* prm = (const float*)d_in[1];
    float* out = (float*)d_out;

    const int total_threads = BB * HO * JSLOTS;  // 130048 = 508 * 256 exactly
    const int blocks = total_threads / 256;
    qconv_fused<<<blocks, 256, 0, stream>>>(x, prm, out);
}

// Round 7
// 66.280 us; speedup vs baseline: 1.1805x; 1.0667x over previous
//
#include <hip/hip_runtime.h>

// QConv2D quanvolution — single fused kernel, parallel setup (R6, resubmit
// after broker timeout).
// Heisenberg picture: z_w(patch) = sum_{P in {I,Y,Z}^4} c_{w,P} * prod_q t_q(P_q),
//   t(I)=1, t(Y)=-sin a_q, t(Z)=cos a_q;  c_{w,P} fixed by params.
// Per-block redundant setup (co-resident blocks; launch fusion won R5):
//   Phase A : wave 0, 4 lanes per U-column (shfl_xor cross-lane gates) -> Ut in LDS
//   Phase B1: M_w = I - 2*sum_{k:bit set} conj(U[k][j])U[k][i]  (8 k-terms, unitarity)
//   Phase B2: 324 coefficient traces (1/thread at 512 threads)
//   Phase C : eval, 4 patches/thread, deduped sincos (10 not 16)
// Wire q <-> state bit (8>>q).  Block=512, grid=254 (exactly 130048 threads).

#define HH 128
#define WW 128
#define HO 127
#define WO 127
#define BB 32
#define JSLOTS 32   // 4-column thread-slots per output row
#define TPB 512

__global__ __launch_bounds__(TPB) void qconv_fused(
    const float* __restrict__ x, const float* __restrict__ prm,
    float* __restrict__ out) {
    __shared__ float Utr[16][20];   // Ut[j][k] = U[k][j]; stride 20: 16B-aligned rows, conflict-free
    __shared__ float Uti[16][20];
    __shared__ float Mr[4][16][17]; // M_w[j][i], padded
    __shared__ float Mi[4][16][17];
    __shared__ float4 sW[81];       // sW[p] = c_{*,P}

    const int tid = threadIdx.x;

    // ---- Phase A: U columns, 4 lanes per column (wave 0) ----
    if (tid < 64) {
        const int c = tid >> 2;   // column j
        const int g = tid & 3;    // amp group: amps 4g..4g+3 (m = amp&3)
        float re[4], im[4];
#pragma unroll
        for (int m = 0; m < 4; ++m) { re[m] = (4 * g + m == c) ? 1.f : 0.f; im[m] = 0.f; }

#pragma unroll
        for (int l = 0; l < 2; ++l) {
            const float* p = prm + l * 8;
            // --- wire0: RX (mask8 -> cross lane^2), RZ (bit = g>>1) ---
            { float s, cc; __sincosf(p[0] * 0.5f, &s, &cc);
              float pr[4], pi[4];
#pragma unroll
              for (int m = 0; m < 4; ++m) { pr[m] = __shfl_xor(re[m], 2); pi[m] = __shfl_xor(im[m], 2); }
#pragma unroll
              for (int m = 0; m < 4; ++m) { re[m] = fmaf(cc, re[m], s * pi[m]); im[m] = fmaf(cc, im[m], -s * pr[m]); } }
            { float sp, cp; __sincosf(p[1] * 0.5f, &sp, &cp);
              const float sg = (g & 2) ? sp : -sp;
#pragma unroll
              for (int m = 0; m < 4; ++m) { float r = re[m], q = im[m];
                  re[m] = fmaf(r, cp, -q * sg); im[m] = fmaf(q, cp, r * sg); } }
            // --- wire1: RX (mask4 -> cross lane^1), RZ (bit = g&1) ---
            { float s, cc; __sincosf(p[2] * 0.5f, &s, &cc);
              float pr[4], pi[4];
#pragma unroll
              for (int m = 0; m < 4; ++m) { pr[m] = __shfl_xor(re[m], 1); pi[m] = __shfl_xor(im[m], 1); }
#pragma unroll
              for (int m = 0; m < 4; ++m) { re[m] = fmaf(cc, re[m], s * pi[m]); im[m] = fmaf(cc, im[m], -s * pr[m]); } }
            { float sp, cp; __sincosf(p[3] * 0.5f, &sp, &cp);
              const float sg = (g & 1) ? sp : -sp;
#pragma unroll
              for (int m = 0; m < 4; ++m) { float r = re[m], q = im[m];
                  re[m] = fmaf(r, cp, -q * sg); im[m] = fmaf(q, cp, r * sg); } }
            // --- wire2: RX (mask2 -> local m^2), RZ (bit = m>>1) ---
            { float s, cc; __sincosf(p[4] * 0.5f, &s, &cc);
              float r0 = re[0], r1 = re[1], r2 = re[2], r3 = re[3];
              float i0 = im[0], i1 = im[1], i2 = im[2], i3 = im[3];
              re[0] = fmaf(cc, r0, s * i2); im[0] = fmaf(cc, i0, -s * r2);
              re[1] = fmaf(cc, r1, s * i3); im[1] = fmaf(cc, i1, -s * r3);
              re[2] = fmaf(cc, r2, s * i0); im[2] = fmaf(cc, i2, -s * r0);
              re[3] = fmaf(cc, r3, s * i1); im[3] = fmaf(cc, i3, -s * r1); }
            { float sp, cp; __sincosf(p[5] * 0.5f, &sp, &cp);
              float r, q;
              r = re[0]; q = im[0]; re[0] = fmaf(r, cp,  q * sp); im[0] = fmaf(q, cp, -r * sp);
              r = re[1]; q = im[1]; re[1] = fmaf(r, cp,  q * sp); im[1] = fmaf(q, cp, -r * sp);
              r = re[2]; q = im[2]; re[2] = fmaf(r, cp, -q * sp); im[2] = fmaf(q, cp,  r * sp);
              r = re[3]; q = im[3]; re[3] = fmaf(r, cp, -q * sp); im[3] = fmaf(q, cp,  r * sp); }
            // --- wire3: RX (mask1 -> local m^1), RZ (bit = m&1) ---
            { float s, cc; __sincosf(p[6] * 0.5f, &s, &cc);
              float r0 = re[0], r1 = re[1], r2 = re[2], r3 = re[3];
              float i0 = im[0], i1 = im[1], i2 = im[2], i3 = im[3];
              re[0] = fmaf(cc, r0, s * i1); im[0] = fmaf(cc, i0, -s * r1);
              re[1] = fmaf(cc, r1, s * i0); im[1] = fmaf(cc, i1, -s * r0);
              re[2] = fmaf(cc, r2, s * i3); im[2] = fmaf(cc, i2, -s * r3);
              re[3] = fmaf(cc, r3, s * i2); im[3] = fmaf(cc, i3, -s * r2); }
            { float sp, cp; __sincosf(p[7] * 0.5f, &sp, &cp);
              float r, q;
              r = re[0]; q = im[0]; re[0] = fmaf(r, cp,  q * sp); im[0] = fmaf(q, cp, -r * sp);
              r = re[1]; q = im[1]; re[1] = fmaf(r, cp, -q * sp); im[1] = fmaf(q, cp,  r * sp);
              r = re[2]; q = im[2]; re[2] = fmaf(r, cp,  q * sp); im[2] = fmaf(q, cp, -r * sp);
              r = re[3]; q = im[3]; re[3] = fmaf(r, cp, -q * sp); im[3] = fmaf(q, cp,  r * sp); }
            // --- CNOT(ctrl bit2 = g&1, tgt bit3): lanes with g&1 swap regs with lane^2 ---
#pragma unroll
            for (int m = 0; m < 4; ++m) {
                float pr = __shfl_xor(re[m], 2), pi = __shfl_xor(im[m], 2);
                if (g & 1) { re[m] = pr; im[m] = pi; }
            }
            // --- CNOT(ctrl bit1 = m>>1, tgt bit2): m=2,3 exchange across lane^1 ---
            re[2] = __shfl_xor(re[2], 1); im[2] = __shfl_xor(im[2], 1);
            re[3] = __shfl_xor(re[3], 1); im[3] = __shfl_xor(im[3], 1);
            // --- CNOT(ctrl bit0 = m&1, tgt bit1): local swap amps 1<->3 ---
            { float t;
              t = re[1]; re[1] = re[3]; re[3] = t;
              t = im[1]; im[1] = im[3]; im[3] = t; }
        }
        // Ut[j=c][k=4g+m] = U[k][c]; row stride 20 floats -> 16B-aligned float4
        *(float4*)&Utr[c][4 * g] = make_float4(re[0], re[1], re[2], re[3]);
        *(float4*)&Uti[c][4 * g] = make_float4(im[0], im[1], im[2], im[3]);
    }
    __syncthreads();

    // ---- Phase B1: M_w[j][i] = delta_ji - 2*sum_{k: k&zbit} conj(U[k][j]) U[k][i] ----
    {
        const int e0 = tid * 2;            // 1024 entries, 2 per thread (i0 even)
        const int w = e0 >> 8;
        const int j = (e0 >> 4) & 15;
        const int i0 = e0 & 15;
        const int zbit = 8 >> w;
        const int lowmask = zbit - 1;
        float sr0 = 0.f, si0 = 0.f, sr1 = 0.f, si1 = 0.f;
#pragma unroll
        for (int t = 0; t < 8; ++t) {
            const int k = ((t & ~lowmask) << 1) | zbit | (t & lowmask);
            const float ar = Utr[j][k],      ai = Uti[j][k];
            const float br0 = Utr[i0][k],    bi0 = Uti[i0][k];
            const float br1 = Utr[i0 + 1][k], bi1 = Uti[i0 + 1][k];
            sr0 += fmaf(ar, br0, ai * bi0);  si0 += fmaf(ar, bi0, -ai * br0);
            sr1 += fmaf(ar, br1, ai * bi1);  si1 += fmaf(ar, bi1, -ai * br1);
        }
        Mr[w][j][i0]     = ((j == i0)     ? 1.f : 0.f) - 2.f * sr0;
        Mi[w][j][i0]     = -2.f * si0;
        Mr[w][j][i0 + 1] = ((j == i0 + 1) ? 1.f : 0.f) - 2.f * sr1;
        Mi[w][j][i0 + 1] = -2.f * si1;
    }
    __syncthreads();

    // ---- Phase B2: coefficient traces (324, one per thread) ----
    if (tid < 324) {
        const int w = tid / 81;
        int p = tid % 81;
        const int pidx = p;
        const int t3 = p % 3; p /= 3;
        const int t2 = p % 3; p /= 3;
        const int t1 = p % 3;
        const int t0 = p / 3;
        const int f = (t0 == 1 ? 8 : 0) | (t1 == 1 ? 4 : 0) |
                      (t2 == 1 ? 2 : 0) | (t3 == 1 ? 1 : 0);
        float acc = 0.f;
        for (int i = 0; i < 16; ++i) {
            // phase = P[i][i^f]; Z: diag(1,-1); Y[0][1]=-i, Y[1][0]=+i.
            float pr = 1.f, pi = 0.f;
            int ib;
            ib = (i >> 3) & 1;
            if (t0 == 2) { if (ib) { pr = -pr; pi = -pi; } }
            else if (t0 == 1) { float tt = pr; if (ib) { pr = -pi; pi = tt; } else { pr = pi; pi = -tt; } }
            ib = (i >> 2) & 1;
            if (t1 == 2) { if (ib) { pr = -pr; pi = -pi; } }
            else if (t1 == 1) { float tt = pr; if (ib) { pr = -pi; pi = tt; } else { pr = pi; pi = -tt; } }
            ib = (i >> 1) & 1;
            if (t2 == 2) { if (ib) { pr = -pr; pi = -pi; } }
            else if (t2 == 1) { float tt = pr; if (ib) { pr = -pi; pi = tt; } else { pr = pi; pi = -tt; } }
            ib = i & 1;
            if (t3 == 2) { if (ib) { pr = -pr; pi = -pi; } }
            else if (t3 == 1) { float tt = pr; if (ib) { pr = -pi; pi = tt; } else { pr = pi; pi = -tt; } }
            const int j = i ^ f;
            acc += pr * Mr[w][j][i] - pi * Mi[w][j][i];
        }
        ((float*)sW)[pidx * 4 + w] = acc * (1.0f / 16.0f);
    }
    __syncthreads();

    // ---- Phase C: eval, 4 consecutive output columns per thread ----
    const int tid_g = blockIdx.x * TPB + tid;   // grid is exactly 254*512
    const int slot = tid_g % JSLOTS;
    int t = tid_g / JSLOTS;
    const int i = t % HO;
    const int b = t / HO;
    const int j0 = slot * 4;   // 16B-aligned

    const float* row0 = x + ((size_t)b * HH + i) * WW + j0;
    const float* row1 = row0 + WW;
    const float4 v0 = *(const float4*)row0;
    const float4 v1 = *(const float4*)row1;
    const bool has5 = (j0 + 4 < WW);
    const float x04 = has5 ? row0[4] : 0.f;
    const float x14 = has5 ? row1[4] : 0.f;
    const float r0[5] = {v0.x, v0.y, v0.z, v0.w, x04};
    const float r1[5] = {v1.x, v1.y, v1.z, v1.w, x14};

    // deduped: 10 sincos for the 10 unique angles
    float s0[5], c0[5], s1[5], c1[5];
#pragma unroll
    for (int u = 0; u < 5; ++u) {
        __sincosf(r0[u], &s0[u], &c0[u]);
        __sincosf(r1[u], &s1[u], &c1[u]);
    }
    float t0v[4][3], t1v[4][3], t2v[4][3], t3v[4][3];
#pragma unroll
    for (int pp = 0; pp < 4; ++pp) {
        t0v[pp][0] = 1.f; t0v[pp][1] = -s0[pp];     t0v[pp][2] = c0[pp];
        t1v[pp][0] = 1.f; t1v[pp][1] = -s0[pp + 1]; t1v[pp][2] = c0[pp + 1];
        t2v[pp][0] = 1.f; t2v[pp][1] = -s1[pp];     t2v[pp][2] = c1[pp];
        t3v[pp][0] = 1.f; t3v[pp][1] = -s1[pp + 1]; t3v[pp][2] = c1[pp + 1];
    }

    float acc[4][4];  // [patch][wire]
#pragma unroll
    for (int pp = 0; pp < 4; ++pp)
#pragma unroll
        for (int w = 0; w < 4; ++w) acc[pp][w] = 0.f;

#pragma unroll
    for (int p0 = 0; p0 < 3; ++p0) {
        float g0[4];
#pragma unroll
        for (int pp = 0; pp < 4; ++pp) g0[pp] = t0v[pp][p0];
#pragma unroll
        for (int p1 = 0; p1 < 3; ++p1) {
            float g1[4];
#pragma unroll
            for (int pp = 0; pp < 4; ++pp) g1[pp] = g0[pp] * t1v[pp][p1];
#pragma unroll
            for (int p2 = 0; p2 < 3; ++p2) {
                float g2[4];
#pragma unroll
                for (int pp = 0; pp < 4; ++pp) g2[pp] = g1[pp] * t2v[pp][p2];
#pragma unroll
                for (int p3 = 0; p3 < 3; ++p3) {
                    const int p = ((p0 * 3 + p1) * 3 + p2) * 3 + p3;
                    const float4 q = sW[p];  // one DS read feeds 4 patches
#pragma unroll
                    for (int pp = 0; pp < 4; ++pp) {
                        const float g = g2[pp] * t3v[pp][p3];
                        acc[pp][0] = fmaf(g, q.x, acc[pp][0]);
                        acc[pp][1] = fmaf(g, q.y, acc[pp][1]);
                        acc[pp][2] = fmaf(g, q.z, acc[pp][2]);
                        acc[pp][3] = fmaf(g, q.w, acc[pp][3]);
                    }
                }
            }
        }
    }

    const int npatch = (j0 + 4 <= WO) ? 4 : (WO - j0);  // slot 31 -> 3
    float* obase = out + (((size_t)b * 4) * HO + (size_t)i) * WO + j0;
#pragma unroll
    for (int w = 0; w < 4; ++w) {
        float* o = obase + (size_t)w * HO * WO;
        for (int pp = 0; pp < npatch; ++pp) o[pp] = acc[pp][w];
    }
}

extern "C" void kernel_launch(void* const* d_in, const int* in_sizes, int n_in,
                              void* d_out, int out_size, void* d_ws, size_t ws_size,
                              hipStream_t stream) {
    const float* x = (const float*)d_in[0];
    const float* prm = (const float*)d_in[1];
    float* out = (float*)d_out;

    const int total_threads = BB * HO * JSLOTS;  // 130048 = 254 * 512 exactly
    const int blocks = total_threads / TPB;
    qconv_fused<<<blocks, TPB, 0, stream>>>(x, prm, out);
}

// Round 8
// 64.993 us; speedup vs baseline: 1.2039x; 1.0198x over previous
//
#include <hip/hip_runtime.h>

// QConv2D quanvolution — single fused kernel, parallel setup, Horner eval (R8).
// Heisenberg picture: z_w(patch) = sum_{P in {I,Y,Z}^4} c_{w,P} * prod_q t_q(P_q),
//   t(I)=1, t(Y)=-sin a_q, t(Z)=cos a_q;  c_{w,P} fixed by params.
// Per-block redundant setup (1 block/CU; launch fusion won R5, parallel setup R7):
//   Phase A : wave 0, 4 lanes per U-column (shfl_xor cross-lane gates) -> Ut in LDS
//   Phase B1: M_w = I - 2*sum_{k:bit set} conj(U[k][j])U[k][i]  (unitarity, 8 terms)
//   Phase B2: 324 coefficient traces -> sW[81] (float4 over output wires)
//   Phase C : eval, 4 patches/thread, inside-out (Horner) contraction:
//             d = q0 + y3*q1 + c3*q2 per base-3 digit level; float4 lanes are the
//             4 output wires, so the final accumulator is the output vector.
//             ~320 VALU/patch vs 441 for the R7 product-tree.
// Wire q <-> state bit (8>>q).  Block=512, grid=254 (exactly 130048 threads).

#define HH 128
#define WW 128
#define HO 127
#define WO 127
#define BB 32
#define JSLOTS 32   // 4-column thread-slots per output row
#define TPB 512

typedef float v4f __attribute__((ext_vector_type(4)));

__global__ __launch_bounds__(TPB) void qconv_fused(
    const float* __restrict__ x, const float* __restrict__ prm,
    float* __restrict__ out) {
    __shared__ float Utr[16][20];   // Ut[j][k] = U[k][j]; stride 20: aligned, conflict-free
    __shared__ float Uti[16][20];
    __shared__ float Mr[4][16][17]; // M_w[j][i], padded
    __shared__ float Mi[4][16][17];
    __shared__ v4f sW[81];          // sW[p] = c_{*,P}, lanes = output wires

    const int tid = threadIdx.x;

    // ---- Phase A: U columns, 4 lanes per column (wave 0) ----
    if (tid < 64) {
        const int c = tid >> 2;   // column j
        const int g = tid & 3;    // amp group: amps 4g..4g+3 (m = amp&3)
        float re[4], im[4];
#pragma unroll
        for (int m = 0; m < 4; ++m) { re[m] = (4 * g + m == c) ? 1.f : 0.f; im[m] = 0.f; }

#pragma unroll
        for (int l = 0; l < 2; ++l) {
            const float* p = prm + l * 8;
            // --- wire0: RX (mask8 -> cross lane^2), RZ (bit = g>>1) ---
            { float s, cc; __sincosf(p[0] * 0.5f, &s, &cc);
              float pr[4], pi[4];
#pragma unroll
              for (int m = 0; m < 4; ++m) { pr[m] = __shfl_xor(re[m], 2); pi[m] = __shfl_xor(im[m], 2); }
#pragma unroll
              for (int m = 0; m < 4; ++m) { re[m] = fmaf(cc, re[m], s * pi[m]); im[m] = fmaf(cc, im[m], -s * pr[m]); } }
            { float sp, cp; __sincosf(p[1] * 0.5f, &sp, &cp);
              const float sg = (g & 2) ? sp : -sp;
#pragma unroll
              for (int m = 0; m < 4; ++m) { float r = re[m], q = im[m];
                  re[m] = fmaf(r, cp, -q * sg); im[m] = fmaf(q, cp, r * sg); } }
            // --- wire1: RX (mask4 -> cross lane^1), RZ (bit = g&1) ---
            { float s, cc; __sincosf(p[2] * 0.5f, &s, &cc);
              float pr[4], pi[4];
#pragma unroll
              for (int m = 0; m < 4; ++m) { pr[m] = __shfl_xor(re[m], 1); pi[m] = __shfl_xor(im[m], 1); }
#pragma unroll
              for (int m = 0; m < 4; ++m) { re[m] = fmaf(cc, re[m], s * pi[m]); im[m] = fmaf(cc, im[m], -s * pr[m]); } }
            { float sp, cp; __sincosf(p[3] * 0.5f, &sp, &cp);
              const float sg = (g & 1) ? sp : -sp;
#pragma unroll
              for (int m = 0; m < 4; ++m) { float r = re[m], q = im[m];
                  re[m] = fmaf(r, cp, -q * sg); im[m] = fmaf(q, cp, r * sg); } }
            // --- wire2: RX (mask2 -> local m^2), RZ (bit = m>>1) ---
            { float s, cc; __sincosf(p[4] * 0.5f, &s, &cc);
              float r0 = re[0], r1 = re[1], r2 = re[2], r3 = re[3];
              float i0 = im[0], i1 = im[1], i2 = im[2], i3 = im[3];
              re[0] = fmaf(cc, r0, s * i2); im[0] = fmaf(cc, i0, -s * r2);
              re[1] = fmaf(cc, r1, s * i3); im[1] = fmaf(cc, i1, -s * r3);
              re[2] = fmaf(cc, r2, s * i0); im[2] = fmaf(cc, i2, -s * r0);
              re[3] = fmaf(cc, r3, s * i1); im[3] = fmaf(cc, i3, -s * r1); }
            { float sp, cp; __sincosf(p[5] * 0.5f, &sp, &cp);
              float r, q;
              r = re[0]; q = im[0]; re[0] = fmaf(r, cp,  q * sp); im[0] = fmaf(q, cp, -r * sp);
              r = re[1]; q = im[1]; re[1] = fmaf(r, cp,  q * sp); im[1] = fmaf(q, cp, -r * sp);
              r = re[2]; q = im[2]; re[2] = fmaf(r, cp, -q * sp); im[2] = fmaf(q, cp,  r * sp);
              r = re[3]; q = im[3]; re[3] = fmaf(r, cp, -q * sp); im[3] = fmaf(q, cp,  r * sp); }
            // --- wire3: RX (mask1 -> local m^1), RZ (bit = m&1) ---
            { float s, cc; __sincosf(p[6] * 0.5f, &s, &cc);
              float r0 = re[0], r1 = re[1], r2 = re[2], r3 = re[3];
              float i0 = im[0], i1 = im[1], i2 = im[2], i3 = im[3];
              re[0] = fmaf(cc, r0, s * i1); im[0] = fmaf(cc, i0, -s * r1);
              re[1] = fmaf(cc, r1, s * i0); im[1] = fmaf(cc, i1, -s * r0);
              re[2] = fmaf(cc, r2, s * i3); im[2] = fmaf(cc, i2, -s * r3);
              re[3] = fmaf(cc, r3, s * i2); im[3] = fmaf(cc, i3, -s * r2); }
            { float sp, cp; __sincosf(p[7] * 0.5f, &sp, &cp);
              float r, q;
              r = re[0]; q = im[0]; re[0] = fmaf(r, cp,  q * sp); im[0] = fmaf(q, cp, -r * sp);
              r = re[1]; q = im[1]; re[1] = fmaf(r, cp, -q * sp); im[1] = fmaf(q, cp,  r * sp);
              r = re[2]; q = im[2]; re[2] = fmaf(r, cp,  q * sp); im[2] = fmaf(q, cp, -r * sp);
              r = re[3]; q = im[3]; re[3] = fmaf(r, cp, -q * sp); im[3] = fmaf(q, cp,  r * sp); }
            // --- CNOT(ctrl bit2 = g&1, tgt bit3): lanes with g&1 take lane^2's regs ---
#pragma unroll
            for (int m = 0; m < 4; ++m) {
                float pr = __shfl_xor(re[m], 2), pi = __shfl_xor(im[m], 2);
                if (g & 1) { re[m] = pr; im[m] = pi; }
            }
            // --- CNOT(ctrl bit1 = m>>1, tgt bit2): m=2,3 exchange across lane^1 ---
            re[2] = __shfl_xor(re[2], 1); im[2] = __shfl_xor(im[2], 1);
            re[3] = __shfl_xor(re[3], 1); im[3] = __shfl_xor(im[3], 1);
            // --- CNOT(ctrl bit0 = m&1, tgt bit1): local swap amps 1<->3 ---
            { float t;
              t = re[1]; re[1] = re[3]; re[3] = t;
              t = im[1]; im[1] = im[3]; im[3] = t; }
        }
        *(float4*)&Utr[c][4 * g] = make_float4(re[0], re[1], re[2], re[3]);
        *(float4*)&Uti[c][4 * g] = make_float4(im[0], im[1], im[2], im[3]);
    }
    __syncthreads();

    // ---- Phase B1: M_w[j][i] = delta_ji - 2*sum_{k: k&zbit} conj(U[k][j]) U[k][i] ----
    {
        const int e0 = tid * 2;            // 1024 entries, 2 per thread (i0 even)
        const int w = e0 >> 8;
        const int j = (e0 >> 4) & 15;
        const int i0 = e0 & 15;
        const int zbit = 8 >> w;
        const int lowmask = zbit - 1;
        float sr0 = 0.f, si0 = 0.f, sr1 = 0.f, si1 = 0.f;
#pragma unroll
        for (int t = 0; t < 8; ++t) {
            const int k = ((t & ~lowmask) << 1) | zbit | (t & lowmask);
            const float ar = Utr[j][k],      ai = Uti[j][k];
            const float br0 = Utr[i0][k],    bi0 = Uti[i0][k];
            const float br1 = Utr[i0 + 1][k], bi1 = Uti[i0 + 1][k];
            sr0 += fmaf(ar, br0, ai * bi0);  si0 += fmaf(ar, bi0, -ai * br0);
            sr1 += fmaf(ar, br1, ai * bi1);  si1 += fmaf(ar, bi1, -ai * br1);
        }
        Mr[w][j][i0]     = ((j == i0)     ? 1.f : 0.f) - 2.f * sr0;
        Mi[w][j][i0]     = -2.f * si0;
        Mr[w][j][i0 + 1] = ((j == i0 + 1) ? 1.f : 0.f) - 2.f * sr1;
        Mi[w][j][i0 + 1] = -2.f * si1;
    }
    __syncthreads();

    // ---- Phase B2: coefficient traces (324, one per thread) ----
    if (tid < 324) {
        const int w = tid / 81;
        int p = tid % 81;
        const int pidx = p;
        const int t3 = p % 3; p /= 3;
        const int t2 = p % 3; p /= 3;
        const int t1 = p % 3;
        const int t0 = p / 3;
        const int f = (t0 == 1 ? 8 : 0) | (t1 == 1 ? 4 : 0) |
                      (t2 == 1 ? 2 : 0) | (t3 == 1 ? 1 : 0);
        float acc = 0.f;
        for (int i = 0; i < 16; ++i) {
            // phase = P[i][i^f]; Z: diag(1,-1); Y[0][1]=-i, Y[1][0]=+i.
            float pr = 1.f, pi = 0.f;
            int ib;
            ib = (i >> 3) & 1;
            if (t0 == 2) { if (ib) { pr = -pr; pi = -pi; } }
            else if (t0 == 1) { float tt = pr; if (ib) { pr = -pi; pi = tt; } else { pr = pi; pi = -tt; } }
            ib = (i >> 2) & 1;
            if (t1 == 2) { if (ib) { pr = -pr; pi = -pi; } }
            else if (t1 == 1) { float tt = pr; if (ib) { pr = -pi; pi = tt; } else { pr = pi; pi = -tt; } }
            ib = (i >> 1) & 1;
            if (t2 == 2) { if (ib) { pr = -pr; pi = -pi; } }
            else if (t2 == 1) { float tt = pr; if (ib) { pr = -pi; pi = tt; } else { pr = pi; pi = -tt; } }
            ib = i & 1;
            if (t3 == 2) { if (ib) { pr = -pr; pi = -pi; } }
            else if (t3 == 1) { float tt = pr; if (ib) { pr = -pi; pi = tt; } else { pr = pi; pi = -tt; } }
            const int j = i ^ f;
            acc += pr * Mr[w][j][i] - pi * Mi[w][j][i];
        }
        ((float*)sW)[pidx * 4 + w] = acc * (1.0f / 16.0f);
    }
    __syncthreads();

    // ---- Phase C: eval, 4 consecutive output columns per thread, Horner ----
    const int tid_g = blockIdx.x * TPB + tid;   // grid is exactly 254*512
    const int slot = tid_g % JSLOTS;
    int t = tid_g / JSLOTS;
    const int i = t % HO;
    const int b = t / HO;
    const int j0 = slot * 4;   // 16B-aligned

    const float* row0 = x + ((size_t)b * HH + i) * WW + j0;
    const float* row1 = row0 + WW;
    const float4 v0 = *(const float4*)row0;
    const float4 v1 = *(const float4*)row1;
    const bool has5 = (j0 + 4 < WW);
    const float x04 = has5 ? row0[4] : 0.f;
    const float x14 = has5 ? row1[4] : 0.f;
    const float r0[5] = {v0.x, v0.y, v0.z, v0.w, x04};
    const float r1[5] = {v1.x, v1.y, v1.z, v1.w, x14};

    // 10 unique angles -> 10 sincos
    float s0[5], c0[5], s1[5], c1[5];
#pragma unroll
    for (int u = 0; u < 5; ++u) {
        __sincosf(r0[u], &s0[u], &c0[u]);
        __sincosf(r1[u], &s1[u], &c1[u]);
    }
    // patch pp wires: w0 angle r0[pp], w1 r0[pp+1], w2 r1[pp], w3 r1[pp+1]
    float y0v[4], c0v[4], y1v[4], c1v[4], y2v[4], c2v[4], y3v[4], c3v[4];
#pragma unroll
    for (int pp = 0; pp < 4; ++pp) {
        y0v[pp] = -s0[pp];     c0v[pp] = c0[pp];
        y1v[pp] = -s0[pp + 1]; c1v[pp] = c0[pp + 1];
        y2v[pp] = -s1[pp];     c2v[pp] = c1[pp];
        y3v[pp] = -s1[pp + 1]; c3v[pp] = c1[pp + 1];
    }

    v4f acc0[4];
#pragma unroll
    for (int p0 = 0; p0 < 3; ++p0) {
        v4f acc1[4];
#pragma unroll
        for (int p1 = 0; p1 < 3; ++p1) {
            v4f acc2[4];
#pragma unroll
            for (int p2 = 0; p2 < 3; ++p2) {
                const int base = ((p0 * 3 + p1) * 3 + p2) * 3;
                const v4f q0 = sW[base], q1 = sW[base + 1], q2 = sW[base + 2];
#pragma unroll
                for (int pp = 0; pp < 4; ++pp) {
                    v4f d = q0 + y3v[pp] * q1 + c3v[pp] * q2;  // 2 v4 fma
                    if (p2 == 0)      acc2[pp] = d;
                    else if (p2 == 1) acc2[pp] += y2v[pp] * d;
                    else              acc2[pp] += c2v[pp] * d;
                }
            }
#pragma unroll
            for (int pp = 0; pp < 4; ++pp) {
                if (p1 == 0)      acc1[pp] = acc2[pp];
                else if (p1 == 1) acc1[pp] += y1v[pp] * acc2[pp];
                else              acc1[pp] += c1v[pp] * acc2[pp];
            }
        }
#pragma unroll
        for (int pp = 0; pp < 4; ++pp) {
            if (p0 == 0)      acc0[pp] = acc1[pp];
            else if (p0 == 1) acc0[pp] += y0v[pp] * acc1[pp];
            else              acc0[pp] += c0v[pp] * acc1[pp];
        }
    }

    const int npatch = (j0 + 4 <= WO) ? 4 : (WO - j0);  // slot 31 -> 3
    float* obase = out + (((size_t)b * 4) * HO + (size_t)i) * WO + j0;
#pragma unroll
    for (int w = 0; w < 4; ++w) {
        float* o = obase + (size_t)w * HO * WO;
        for (int pp = 0; pp < npatch; ++pp) o[pp] = acc0[pp][w];
    }
}

extern "C" void kernel_launch(void* const* d_in, const int* in_sizes, int n_in,
                              void* d_out, int out_size, void* d_ws, size_t ws_size,
                              hipStream_t stream) {
    const float* x = (const float*)d_in[0];
    const float* prm = (const float*)d_in[1];
    float* out = (float*)d_out;

    const int total_threads = BB * HO * JSLOTS;  // 130048 = 254 * 512 exactly
    const int blocks = total_threads / TPB;
    qconv_fused<<<blocks, TPB, 0, stream>>>(x, prm, out);
}